// Round 2
// baseline (487.680 us; speedup 1.0000x reference)
//
#include <hip/hip_runtime.h>
#include <hip/hip_fp16.h>

#define BB   2
#define NN   50000
#define EE   800000
#define INCH 64
#define C1   16
#define C2   32
#define NB   (BB*NN)
#define NODE2 (2*NN)                 // layer1 + layer2 degree counters
#define NBLK2 ((NODE2 + 255)/256)    // scan blocks = 391

// workspace layout (float-unit offsets)
#define OFF_XS1   0                          // NB*C1 halves = NB*C1/2 floats
#define OFF_XS2   (OFF_XS1 + NB*C1/2)        // NB*C2 halves
#define OFF_DOTK1 (OFF_XS2 + NB*C2/2)
#define OFF_DOTQ1 (OFF_DOTK1 + NB)
#define OFF_DOTK2 (OFF_DOTQ1 + NB)
#define OFF_DOTQ2 (OFF_DOTK2 + NB)
#define OFF_AG1   (OFF_DOTQ2 + NB)           // NN*32 floats [node][cp][4]
#define OFF_AG2   (OFF_AG1 + NN*32)          // NN*64 floats
#define OFF_DEG   (OFF_AG2 + NN*64)          // NODE2 u32
#define OFF_START (OFF_DEG + NODE2)          // NODE2 u32
#define OFF_CUR   (OFF_START + NODE2)        // NODE2 u32
#define OFF_BSUM  (OFF_CUR + NODE2)          // 512 u32
#define OFF_SLOT  (OFF_BSUM + 512)           // 2*EE u32 edge ids
#define OFF_SC    (OFF_SLOT + 2*EE)          // sc[0]=ec1, sc[1]=ec2

__device__ __forceinline__ float sigmoidf(float x) {
    return 1.0f / (1.0f + __expf(-x));
}

// ---------------- tiny scalar precompute -------------------------------------
__global__ void k_sc(const float* __restrict__ we1, const float* __restrict__ aw1,
                     const float* __restrict__ we2, const float* __restrict__ aw2,
                     float* __restrict__ sc) {
    if (threadIdx.x == 0) {
        float e = 0.f;
        for (int j = 0; j < C1; ++j) e += we1[j] * aw1[2*C1+j];
        sc[0] = e;
    }
    if (threadIdx.x == 1) {
        float e = 0.f;
        for (int j = 0; j < C2; ++j) e += we2[j] * aw2[2*C2+j];
        sc[1] = e;
    }
}

// ---------------- CSR build: histogram / scan / scatter ----------------------
__global__ __launch_bounds__(256) void k_hist(
        const int* __restrict__ ei0, const int* __restrict__ ei1,
        unsigned* __restrict__ deg) {
    int t = blockIdx.x * 256 + threadIdx.x;
    if (t >= 2*EE) return;
    int dst, base;
    if (t < EE) { dst = ei0[EE + t];        base = 0;  }
    else        { dst = ei1[EE + (t - EE)]; base = NN; }
    atomicAdd(&deg[base + dst], 1u);
}

__global__ __launch_bounds__(256) void k_scanA(
        const unsigned* __restrict__ deg, unsigned* __restrict__ start,
        unsigned* __restrict__ bsum) {
    __shared__ unsigned s[256];
    int tid = threadIdx.x;
    int g = blockIdx.x * 256 + tid;
    unsigned v = (g < NODE2) ? deg[g] : 0u;
    s[tid] = v;
    __syncthreads();
    for (int o = 1; o < 256; o <<= 1) {
        unsigned t = (tid >= o) ? s[tid - o] : 0u;
        __syncthreads();
        s[tid] += t;
        __syncthreads();
    }
    if (g < NODE2) start[g] = s[tid] - v;       // exclusive within block
    if (tid == 255) bsum[blockIdx.x] = s[tid];  // block total
}

__global__ __launch_bounds__(512) void k_scanB(unsigned* __restrict__ bsum) {
    __shared__ unsigned s[512];
    int tid = threadIdx.x;
    unsigned v = (tid < NBLK2) ? bsum[tid] : 0u;
    s[tid] = v;
    __syncthreads();
    for (int o = 1; o < 512; o <<= 1) {
        unsigned t = (tid >= o) ? s[tid - o] : 0u;
        __syncthreads();
        s[tid] += t;
        __syncthreads();
    }
    if (tid < NBLK2) bsum[tid] = s[tid] - v;    // exclusive block offsets
}

__global__ __launch_bounds__(256) void k_scanC(
        unsigned* __restrict__ start, const unsigned* __restrict__ bsum,
        unsigned* __restrict__ cursor) {
    int g = blockIdx.x * 256 + threadIdx.x;
    if (g >= NODE2) return;
    unsigned v = start[g] + bsum[blockIdx.x];
    start[g]  = v;
    cursor[g] = v;
}

__global__ __launch_bounds__(256) void k_scatter(
        const int* __restrict__ ei0, const int* __restrict__ ei1,
        unsigned* __restrict__ cursor, unsigned* __restrict__ slot) {
    int t = blockIdx.x * 256 + threadIdx.x;
    if (t >= 2*EE) return;
    int e, dst, base;
    if (t < EE) { e = t;      dst = ei0[EE + e]; base = 0;  }
    else        { e = t - EE; dst = ei1[EE + e]; base = NN; }
    unsigned pos = atomicAdd(&cursor[base + dst], 1u);
    slot[pos] = (unsigned)e;
}

// ---------------- layer 1: xs1 = X @ value1 (half-packed out) ----------------
__global__ __launch_bounds__(256) void k_value1(
        const float* __restrict__ X, const float* __restrict__ value1,
        const float* __restrict__ key1, const float* __restrict__ query1,
        const float* __restrict__ aw1,
        __half* __restrict__ xs1h, float* __restrict__ dotk1, float* __restrict__ dotq1) {
    __shared__ float W[INCH*C1];
    __shared__ float KV[C1], QV[C1];
    int tid = threadIdx.x;
    for (int i = tid; i < INCH*C1; i += 256) W[i] = value1[i];
    if (tid < C1) {
        float kv = 0.f, qv = 0.f;
#pragma unroll
        for (int j = 0; j < C1; ++j) {
            kv += key1[tid*C1+j]   * aw1[j];
            qv += query1[tid*C1+j] * aw1[C1+j];
        }
        KV[tid] = kv; QV[tid] = qv;
    }
    __syncthreads();
    int bn = blockIdx.x * 256 + tid;
    if (bn >= NB) return;
    int b = (bn >= NN) ? 1 : 0;
    int node = bn - b*NN;
    const float4* Xr = (const float4*)(X + (size_t)bn * INCH);
    float acc[C1];
#pragma unroll
    for (int j = 0; j < C1; ++j) acc[j] = 0.f;
#pragma unroll
    for (int v = 0; v < 16; ++v) {
        float4 p = Xr[v];
        float x4[4] = {p.x, p.y, p.z, p.w};
#pragma unroll
        for (int h = 0; h < 4; ++h) {
            int i = v*4 + h;
            float xv = x4[h];
#pragma unroll
            for (int j = 0; j < C1; ++j) acc[j] += xv * W[i*C1+j];
        }
    }
    float dk = 0.f, dq = 0.f;
#pragma unroll
    for (int j = 0; j < C1; ++j) { dk += acc[j]*KV[j]; dq += acc[j]*QV[j]; }
    __half* o = xs1h + ((size_t)node * C1) * 2 + b;
#pragma unroll
    for (int j = 0; j < C1; ++j) o[2*j] = __float2half_rn(acc[j]);
    dotk1[node*2 + b] = dk; dotq1[node*2 + b] = dq;
}

// ---------------- layer-1 gather aggregation: 8 lanes/node, pipelined --------
__global__ __launch_bounds__(256) void k_aggr1(
        const int* __restrict__ ei, const float* __restrict__ ew,
        const float* __restrict__ we, const float* __restrict__ ab,
        const float* __restrict__ sc,
        const uint2* __restrict__ xsh, const float* __restrict__ dotk,
        const float* __restrict__ dotq,
        const unsigned* __restrict__ start, const unsigned* __restrict__ deg,
        const unsigned* __restrict__ slot, float* __restrict__ aggrf) {
    int t = blockIdx.x * 256 + threadIdx.x;
    int node = t >> 3;
    int cp = t & 7;
    if (node >= NN) return;
    unsigned s0 = start[node];
    unsigned n  = deg[node];
    float w0 = we[2*cp], w1 = we[2*cp+1];
    float ec = sc[0], bias = ab[0];
    float2 dk = *(const float2*)(dotk + node*2);
    float acc0 = 0.f, acc1 = 0.f, acc2 = 0.f, acc3 = 0.f;
    // software-pipelined: slot->ei/ew for edge i+1 issued during edge i math
    int src = 0; float ef = 0.f;
    if (n > 0) {
        int eid = (int)slot[s0];
        src = ei[eid]; ef = ew[eid];
    }
    for (unsigned i = 0; i < n; ++i) {
        int src_c = src; float ef_c = ef;
        if (i + 1 < n) {
            int eid = (int)slot[s0 + i + 1];
            src = ei[eid]; ef = ew[eid];
        }
        float2 dq = *(const float2*)(dotq + src_c*2);
        uint2 xr = xsh[(size_t)src_c*8 + cp];
        float se0 = sigmoidf(ef_c * w0);
        float se1 = sigmoidf(ef_c * w1);
        float eb  = ef_c * ec + bias;
        float a0 = sigmoidf(dk.x + dq.x + eb);
        float a1 = sigmoidf(dk.y + dq.y + eb);
        float2 f0 = __half22float2(__builtin_bit_cast(__half2, xr.x));
        float2 f1 = __half22float2(__builtin_bit_cast(__half2, xr.y));
        acc0 += a0 * se0 * f0.x;
        acc1 += a1 * se0 * f0.y;
        acc2 += a0 * se1 * f1.x;
        acc3 += a1 * se1 * f1.y;
    }
    ((float4*)aggrf)[(size_t)node*8 + cp] = make_float4(acc0, acc1, acc2, acc3);
}

// ---------------- fused: update1 + leaky_relu + xs2 = X1 @ value2 ------------
__global__ __launch_bounds__(256) void k_update1(
        const float* __restrict__ cat_w, const float* __restrict__ cat_b,
        const float* __restrict__ value2,
        const float* __restrict__ key2, const float* __restrict__ query2,
        const float* __restrict__ aw2,
        const __half* __restrict__ xs1h, const float* __restrict__ aggr1f,
        __half* __restrict__ xs2h, float* __restrict__ dotk2, float* __restrict__ dotq2) {
    __shared__ float CW[2*C1*C1];
    __shared__ float CB[C1];
    __shared__ float V2[C1*C2];
    __shared__ float KV[C2], QV[C2];
    int tid = threadIdx.x;
    for (int i = tid; i < 2*C1*C1; i += 256) CW[i] = cat_w[i];
    for (int i = tid; i < C1*C2;   i += 256) V2[i] = value2[i];
    if (tid < C1) CB[tid] = cat_b[tid];
    if (tid < C2) {
        float kv = 0.f;
#pragma unroll
        for (int j = 0; j < C2; ++j) kv += key2[tid*C2+j] * aw2[j];
        KV[tid] = kv;
    } else if (tid < 2*C2) {
        int c = tid - C2;
        float qv = 0.f;
#pragma unroll
        for (int j = 0; j < C2; ++j) qv += query2[c*C2+j] * aw2[C2+j];
        QV[c] = qv;
    }
    __syncthreads();
    int bn = blockIdx.x * 256 + tid;
    if (bn >= NB) return;
    int b = (bn >= NN) ? 1 : 0;
    int node = bn - b*NN;
    const __half* xr = xs1h + ((size_t)node*C1)*2 + b;
    const float* agp = aggr1f + (size_t)node*32;
    float xd[C1], ag[C1];
#pragma unroll
    for (int i = 0; i < C1; ++i) xd[i] = __half2float(xr[2*i]);
#pragma unroll
    for (int i = 0; i < C1; ++i) ag[i] = agp[(i>>1)*4 + (i&1)*2 + b];
    float x1[C1];
#pragma unroll
    for (int j = 0; j < C1; ++j) {
        float u = CB[j];
#pragma unroll
        for (int i = 0; i < C1; ++i) {
            u += xd[i] * CW[i*C1 + j];
            u += ag[i] * CW[(C1+i)*C1 + j];
        }
        float o = xd[j] + fmaxf(u, 0.f);
        x1[j] = (o > 0.f) ? o : 0.01f * o;       // leaky_relu
    }
    float o2[C2];
#pragma unroll
    for (int k = 0; k < C2; ++k) o2[k] = 0.f;
#pragma unroll
    for (int j = 0; j < C1; ++j) {
        float xv = x1[j];
#pragma unroll
        for (int k = 0; k < C2; ++k) o2[k] += xv * V2[j*C2 + k];
    }
    float dk = 0.f, dq = 0.f;
#pragma unroll
    for (int k = 0; k < C2; ++k) { dk += o2[k]*KV[k]; dq += o2[k]*QV[k]; }
    __half* o = xs2h + ((size_t)node*C2)*2 + b;
#pragma unroll
    for (int k = 0; k < C2; ++k) o[2*k] = __float2half_rn(o2[k]);
    dotk2[node*2 + b] = dk; dotq2[node*2 + b] = dq;
}

// ---------------- layer-2 gather aggregation: 16 lanes/node, pipelined -------
__global__ __launch_bounds__(256) void k_aggr2(
        const int* __restrict__ ei, const float* __restrict__ ew,
        const float* __restrict__ we, const float* __restrict__ ab,
        const float* __restrict__ sc,
        const uint2* __restrict__ xsh, const float* __restrict__ dotk,
        const float* __restrict__ dotq,
        const unsigned* __restrict__ start, const unsigned* __restrict__ deg,
        const unsigned* __restrict__ slot, float* __restrict__ aggrf) {
    int t = blockIdx.x * 256 + threadIdx.x;
    int node = t >> 4;
    int cp = t & 15;
    if (node >= NN) return;
    unsigned s0 = start[NN + node];
    unsigned n  = deg[NN + node];
    float w0 = we[2*cp], w1 = we[2*cp+1];
    float ec = sc[1], bias = ab[0];
    float2 dk = *(const float2*)(dotk + node*2);
    float acc0 = 0.f, acc1 = 0.f, acc2 = 0.f, acc3 = 0.f;
    int src = 0; float ef = 0.f;
    if (n > 0) {
        int eid = (int)slot[s0];
        src = ei[eid]; ef = ew[eid];
    }
    for (unsigned i = 0; i < n; ++i) {
        int src_c = src; float ef_c = ef;
        if (i + 1 < n) {
            int eid = (int)slot[s0 + i + 1];
            src = ei[eid]; ef = ew[eid];
        }
        float2 dq = *(const float2*)(dotq + src_c*2);
        uint2 xr = xsh[(size_t)src_c*16 + cp];
        float se0 = sigmoidf(ef_c * w0);
        float se1 = sigmoidf(ef_c * w1);
        float eb  = ef_c * ec + bias;
        float a0 = sigmoidf(dk.x + dq.x + eb);
        float a1 = sigmoidf(dk.y + dq.y + eb);
        float2 f0 = __half22float2(__builtin_bit_cast(__half2, xr.x));
        float2 f1 = __half22float2(__builtin_bit_cast(__half2, xr.y));
        acc0 += a0 * se0 * f0.x;
        acc1 += a1 * se0 * f0.y;
        acc2 += a0 * se1 * f1.x;
        acc3 += a1 * se1 * f1.y;
    }
    ((float4*)aggrf)[(size_t)node*16 + cp] = make_float4(acc0, acc1, acc2, acc3);
}

// ---------------- final: update2 -> fp32 out [b][node][c] --------------------
__global__ __launch_bounds__(256) void k_update2(
        const float* __restrict__ cat_w, const float* __restrict__ cat_b,
        const __half* __restrict__ xs2h, const float* __restrict__ aggr2f,
        float* __restrict__ out) {
    __shared__ float CW[2*C2*C2];
    __shared__ float CB[C2];
    int tid = threadIdx.x;
    for (int i = tid; i < 2*C2*C2; i += 256) CW[i] = cat_w[i];
    if (tid < C2) CB[tid] = cat_b[tid];
    __syncthreads();
    int bn = blockIdx.x * 256 + tid;
    if (bn >= NB) return;
    int b = (bn >= NN) ? 1 : 0;
    int node = bn - b*NN;
    const __half* xr = xs2h + ((size_t)node*C2)*2 + b;
    const float* agp = aggr2f + (size_t)node*64;
    float xd[C2], ag[C2];
#pragma unroll
    for (int i = 0; i < C2; ++i) xd[i] = __half2float(xr[2*i]);
#pragma unroll
    for (int i = 0; i < C2; ++i) ag[i] = agp[(i>>1)*4 + (i&1)*2 + b];
    float o[C2];
#pragma unroll
    for (int k = 0; k < C2; ++k) {
        float u = CB[k];
#pragma unroll
        for (int i = 0; i < C2; ++i) {
            u += xd[i] * CW[i*C2 + k];
            u += ag[i] * CW[(C2+i)*C2 + k];
        }
        o[k] = xd[k] + fmaxf(u, 0.f);
    }
    float4* dst = (float4*)(out + (size_t)bn * C2);
#pragma unroll
    for (int v = 0; v < 8; ++v)
        dst[v] = make_float4(o[4*v], o[4*v+1], o[4*v+2], o[4*v+3]);
}

extern "C" void kernel_launch(void* const* d_in, const int* in_sizes, int n_in,
                              void* d_out, int out_size, void* d_ws, size_t ws_size,
                              hipStream_t stream) {
    const float* X      = (const float*)d_in[0];
    const int*   ei0    = (const int*)d_in[1];
    const int*   ei1    = (const int*)d_in[2];
    const float* ew0    = (const float*)d_in[3];
    const float* ew1    = (const float*)d_in[4];
    // d_in[5], d_in[6]: res_n_id0/1 == arange(N) -> identity gather, unused
    const float* value1 = (const float*)d_in[7];
    const float* key1   = (const float*)d_in[8];
    const float* query1 = (const float*)d_in[9];
    const float* we1    = (const float*)d_in[10];
    const float* aw1    = (const float*)d_in[11];
    const float* ab1    = (const float*)d_in[12];
    const float* cw1    = (const float*)d_in[13];
    const float* cb1    = (const float*)d_in[14];
    const float* value2 = (const float*)d_in[15];
    const float* key2   = (const float*)d_in[16];
    const float* query2 = (const float*)d_in[17];
    const float* we2    = (const float*)d_in[18];
    const float* aw2    = (const float*)d_in[19];
    const float* ab2    = (const float*)d_in[20];
    const float* cw2    = (const float*)d_in[21];
    const float* cb2    = (const float*)d_in[22];
    float* ws  = (float*)d_ws;
    float* out = (float*)d_out;

    __half* xs1h = (__half*)(ws + OFF_XS1);
    __half* xs2h = (__half*)(ws + OFF_XS2);
    float* aggr1f = ws + OFF_AG1;
    float* aggr2f = ws + OFF_AG2;
    unsigned* deg    = (unsigned*)(ws + OFF_DEG);
    unsigned* start  = (unsigned*)(ws + OFF_START);
    unsigned* cursor = (unsigned*)(ws + OFF_CUR);
    unsigned* bsum   = (unsigned*)(ws + OFF_BSUM);
    unsigned* slot   = (unsigned*)(ws + OFF_SLOT);

    // zero degree counters only (400 KB)
    (void)hipMemsetAsync(deg, 0, (size_t)NODE2 * sizeof(unsigned), stream);

    k_sc<<<1, 64, 0, stream>>>(we1, aw1, we2, aw2, ws + OFF_SC);

    // CSR build for both layers (independent of node features)
    k_hist<<<(2*EE+255)/256, 256, 0, stream>>>(ei0, ei1, deg);
    k_scanA<<<NBLK2, 256, 0, stream>>>(deg, start, bsum);
    k_scanB<<<1, 512, 0, stream>>>(bsum);
    k_scanC<<<NBLK2, 256, 0, stream>>>(start, bsum, cursor);
    k_scatter<<<(2*EE+255)/256, 256, 0, stream>>>(ei0, ei1, cursor, slot);

    k_value1<<<(NB+255)/256, 256, 0, stream>>>(X, value1, key1, query1, aw1,
                                               xs1h, ws + OFF_DOTK1, ws + OFF_DOTQ1);
    k_aggr1<<<(NN*8+255)/256, 256, 0, stream>>>(ei0, ew0, we1, ab1, ws + OFF_SC,
                                                (const uint2*)xs1h,
                                                ws + OFF_DOTK1, ws + OFF_DOTQ1,
                                                start, deg, slot, aggr1f);
    k_update1<<<(NB+255)/256, 256, 0, stream>>>(cw1, cb1, value2, key2, query2, aw2,
                                                xs1h, aggr1f,
                                                xs2h, ws + OFF_DOTK2, ws + OFF_DOTQ2);
    k_aggr2<<<(NN*16+255)/256, 256, 0, stream>>>(ei1, ew1, we2, ab2, ws + OFF_SC,
                                                 (const uint2*)xs2h,
                                                 ws + OFF_DOTK2, ws + OFF_DOTQ2,
                                                 start, deg, slot, aggr2f);
    k_update2<<<(NB+255)/256, 256, 0, stream>>>(cw2, cb2, xs2h, aggr2f, out);
}